// Round 3
// baseline (210.187 us; speedup 1.0000x reference)
//
#include <hip/hip_runtime.h>
#include <math.h>

// N_AGENTS=16, RNN_H=64, N_HEADS=4, GAT_D=32, EMB=32, SDIM=128, B=4096 rows

typedef __attribute__((ext_vector_type(8))) short short8;
typedef __attribute__((ext_vector_type(8))) unsigned short ushort8;
typedef __attribute__((ext_vector_type(4))) float float4v;

static __device__ inline unsigned short f2bf(float f) {
    unsigned int x;
    __builtin_memcpy(&x, &f, 4);
    unsigned int r = x + 0x7fffu + ((x >> 16) & 1u);   // RNE
    return (unsigned short)(r >> 16);
}

// ---------------------------------------------------------------------------
// K0a: transposes to bf16: w1s_W[0:128][4096] -> w1sT [c][k]; W_gat[64][128]
// -> WgT [c][k].  65 blocks: 0..63 = w1sT 64-col tiles, 64 = WgT.
// ---------------------------------------------------------------------------
__global__ __launch_bounds__(256) void k0a_transpose(
    const float* __restrict__ w1s_W,
    const float* __restrict__ W_gat,
    unsigned short* __restrict__ w1sT,   // [4096][128]
    unsigned short* __restrict__ WgT)    // [128][64]
{
    __shared__ __align__(16) unsigned short Ts[9216];
    const int tid = threadIdx.x;
    if (blockIdx.x < 64) {
        const int c0 = blockIdx.x * 64;
        #pragma unroll
        for (int t = 0; t < 32; ++t) {
            int i = t * 256 + tid;
            int k = i >> 6, cc = i & 63;
            Ts[cc * 136 + k] = f2bf(w1s_W[(size_t)k * 4096 + c0 + cc]);
        }
        __syncthreads();
        #pragma unroll
        for (int t = 0; t < 4; ++t) {
            int i = t * 256 + tid;
            int cc = i >> 4, seg = i & 15;
            *(ushort8*)&w1sT[(size_t)(c0 + cc) * 128 + seg * 8] =
                *(const ushort8*)&Ts[cc * 136 + seg * 8];
        }
    } else {
        #pragma unroll
        for (int t = 0; t < 32; ++t) {
            int i = t * 256 + tid;
            int k = i >> 7, c = i & 127;
            Ts[c * 72 + k] = f2bf(W_gat[k * 128 + c]);
        }
        __syncthreads();
        #pragma unroll
        for (int t = 0; t < 4; ++t) {
            int i = t * 256 + tid;
            int c = i >> 3, seg = i & 7;
            *(ushort8*)&WgT[c * 64 + seg * 8] = *(const ushort8*)&Ts[c * 72 + seg * 8];
        }
    }
}

// ---------------------------------------------------------------------------
// K0b: straight bf16 converts: hidden_states (4194304) + states (524288)
// unit = 8 elements; 589824 units; grid 2304 x 256
// ---------------------------------------------------------------------------
__global__ __launch_bounds__(256) void k0b_convert(
    const float* __restrict__ hidden_states,
    const float* __restrict__ states,
    unsigned short* __restrict__ hs_bf,
    unsigned short* __restrict__ A_bf)
{
    int u = blockIdx.x * 256 + threadIdx.x;
    const float* src;
    unsigned short* dst;
    if (u < 524288) { src = hidden_states + (size_t)u * 8; dst = hs_bf + (size_t)u * 8; }
    else { int u2 = u - 524288; src = states + (size_t)u2 * 8; dst = A_bf + (size_t)u2 * 8; }
    float4 f0 = *(const float4*)src;
    float4 f1 = *(const float4*)(src + 4);
    ushort8 o;
    o[0] = f2bf(f0.x); o[1] = f2bf(f0.y); o[2] = f2bf(f0.z); o[3] = f2bf(f0.w);
    o[4] = f2bf(f1.x); o[5] = f2bf(f1.y); o[6] = f2bf(f1.z); o[7] = f2bf(f1.w);
    *(ushort8*)dst = o;
}

// ---------------------------------------------------------------------------
// K1: GAT via MFMA hp + register softmax + VALU g-einsum + small GEMVs.
// block = 4 batch rows (64 agent rows); grid 1024.
// MFMA A/B frags loaded DIRECTLY from global (WgT is 16KB, L1-hot).
// hp LDS layout: [row][h*36 + d], row stride 144 (banks spread across h).
// ---------------------------------------------------------------------------
__global__ __launch_bounds__(256) void k1_gat(
    const unsigned short* __restrict__ hs_bf,   // [4096*16][64]
    const unsigned short* __restrict__ WgT,     // [128][64]
    const float* __restrict__ states,
    const float* __restrict__ att_a,
    const float* __restrict__ b1_W, const float* __restrict__ b1_b,
    const float* __restrict__ wf_W, const float* __restrict__ wf_b,
    const float* __restrict__ V1_W, const float* __restrict__ V1_b,
    const float* __restrict__ V2_W, const float* __restrict__ V2_b,
    unsigned short* __restrict__ g_bf,          // [B][4][16][32]
    float* __restrict__ b1v, float* __restrict__ wfv, float* __restrict__ vv)
{
    const int b0 = blockIdx.x * 4, tid = threadIdx.x;
    const int wave = tid >> 6, lane = tid & 63, m = lane & 15, quad = lane >> 4;
    __shared__ __align__(16) float hp[64 * 144];
    __shared__ float sv[512];
    __shared__ float dstv[4 * 68];
    __shared__ float red[128];

    sv[tid]       = states[(size_t)b0 * 128 + tid];
    sv[tid + 256] = states[(size_t)b0 * 128 + tid + 256];

    // ---- MFMA: hp[64 rows][128 c], wave w = batch row w ----
    {
        const size_t arow = ((size_t)(b0 + wave) * 16 + m) * 64;
        short8 a0 = *(const short8*)&hs_bf[arow + quad * 8];
        short8 a1 = *(const short8*)&hs_bf[arow + 32 + quad * 8];
        float4v acc[8];
        #pragma unroll
        for (int nt = 0; nt < 8; ++nt) acc[nt] = (float4v){0.f, 0.f, 0.f, 0.f};
        #pragma unroll
        for (int nt = 0; nt < 8; ++nt) {
            const int c = nt * 16 + m;
            short8 bf0 = *(const short8*)&WgT[c * 64 + quad * 8];
            short8 bf1 = *(const short8*)&WgT[c * 64 + 32 + quad * 8];
            acc[nt] = __builtin_amdgcn_mfma_f32_16x16x32_bf16(a0, bf0, acc[nt], 0, 0, 0);
            acc[nt] = __builtin_amdgcn_mfma_f32_16x16x32_bf16(a1, bf1, acc[nt], 0, 0, 0);
        }
        #pragma unroll
        for (int nt = 0; nt < 8; ++nt) {
            const int c = nt * 16 + m, h = c >> 5, d = c & 31;
            #pragma unroll
            for (int reg = 0; reg < 4; ++reg)
                hp[(wave * 16 + quad * 4 + reg) * 144 + h * 36 + d] = acc[nt][reg];
        }
    }
    __syncthreads();

    // ---- attention: thread = (bb = tid>>6, h = (tid>>4)&3, i = tid&15) ----
    const int bb = tid >> 6, h = (tid >> 4) & 3, ii = tid & 15;
    float src = 0.f, dst = 0.f;
    {
        const float* hrow = &hp[(bb * 16 + ii) * 144 + h * 36];
        #pragma unroll
        for (int s = 0; s < 8; ++s) {
            float4 v = *(const float4*)&hrow[s * 4];
            float4 as = *(const float4*)&att_a[h * 64 + s * 4];
            float4 ad = *(const float4*)&att_a[h * 64 + 32 + s * 4];
            src += v.x * as.x + v.y * as.y + v.z * as.z + v.w * as.w;
            dst += v.x * ad.x + v.y * ad.y + v.z * ad.z + v.w * ad.w;
        }
        dstv[bb * 68 + h * 17 + ii] = dst;
    }
    __syncthreads();

    {
        float ev[16], mx = -1e30f;
        #pragma unroll
        for (int j = 0; j < 16; ++j) {
            float x = src + dstv[bb * 68 + h * 17 + j];
            x = (x >= 0.f) ? x : 0.2f * x;
            ev[j] = x; mx = fmaxf(mx, x);
        }
        float ssum = 0.f;
        #pragma unroll
        for (int j = 0; j < 16; ++j) { float p = expf(ev[j] - mx); ev[j] = p; ssum += p; }
        const float inv = 1.f / ssum;

        float ga[32] = {};
        #pragma unroll
        for (int j = 0; j < 16; ++j) {
            const float p = ev[j];
            const float* hj = &hp[(bb * 16 + j) * 144 + h * 36];
            #pragma unroll
            for (int s = 0; s < 8; ++s) {
                float4 v = *(const float4*)&hj[s * 4];
                ga[s * 4 + 0] = fmaf(p, v.x, ga[s * 4 + 0]);
                ga[s * 4 + 1] = fmaf(p, v.y, ga[s * 4 + 1]);
                ga[s * 4 + 2] = fmaf(p, v.z, ga[s * 4 + 2]);
                ga[s * 4 + 3] = fmaf(p, v.w, ga[s * 4 + 3]);
            }
        }
        #pragma unroll
        for (int s = 0; s < 4; ++s) {
            ushort8 o;
            #pragma unroll
            for (int j = 0; j < 8; ++j) {
                float x = ga[s * 8 + j] * inv;
                x = (x > 0.f) ? x : expm1f(x);
                o[j] = f2bf(x);
            }
            *(ushort8*)&g_bf[((size_t)(b0 + bb) * 4 + h) * 512 + ii * 32 + s * 8] = o;
        }
    }

    // ---- small GEMVs: grp = p>>5: bb = grp&3, which = grp>>2 ----
    for (int p = tid; p < 384; p += 256) {
        const int e = p & 31, grp = p >> 5, bbx = grp & 3, which = grp >> 2;
        const float* Wm = (which == 0) ? b1_W : ((which == 1) ? wf_W : V1_W);
        float acc = 0.f;
        #pragma unroll 8
        for (int k = 0; k < 128; ++k) acc = fmaf(sv[bbx * 128 + k], Wm[k * 32 + e], acc);
        const int r = (b0 + bbx) * 32 + e;
        if (which == 0)      b1v[r] = acc + b1_b[e];
        else if (which == 1) wfv[r] = fabsf(acc + wf_b[e]);
        else                 red[bbx * 32 + e] = fmaxf(acc + V1_b[e], 0.f) * V2_W[e];
    }
    __syncthreads();
    if (tid < 4) {
        float acc = V2_b[0];
        #pragma unroll
        for (int e = 0; e < 32; ++e) acc += red[tid * 32 + e];
        vv[b0 + tid] = acc;
    }
}

// ---------------------------------------------------------------------------
// K2a: w1state_bf = bf16( s_aug @ w1s_W + b )  via MFMA, K=128 + fp32 fixup
// for k=128 (uncertainty). 128x128 tile; frags direct from global; LDS only
// as store-stage (33KB -> 4 blocks/CU). grid (32,32).
// ---------------------------------------------------------------------------
__global__ __launch_bounds__(256) void k2a_gemm(
    const unsigned short* __restrict__ A_bf,    // [4096][128]
    const unsigned short* __restrict__ w1sT,    // [4096][128]
    const float* __restrict__ uncertainty,      // [4096]
    const float* __restrict__ w1s_W,            // row 128
    const float* __restrict__ w1s_b,
    unsigned short* __restrict__ w1state_bf)    // [4096][4096]
{
    const int r0 = blockIdx.x * 128, c0 = blockIdx.y * 128;
    const int tid = threadIdx.x;
    const int wave = tid >> 6, lane = tid & 63, m = lane & 15, quad = lane >> 4;
    __shared__ __align__(16) unsigned short Cs[128 * 136];

    float4v acc[2][8];
    #pragma unroll
    for (int mt = 0; mt < 2; ++mt)
        #pragma unroll
        for (int nt = 0; nt < 8; ++nt) acc[mt][nt] = (float4v){0.f, 0.f, 0.f, 0.f};

    #pragma unroll
    for (int ks = 0; ks < 4; ++ks) {
        short8 a0 = *(const short8*)&A_bf[(size_t)(r0 + wave * 32 + m) * 128 + ks * 32 + quad * 8];
        short8 a1 = *(const short8*)&A_bf[(size_t)(r0 + wave * 32 + 16 + m) * 128 + ks * 32 + quad * 8];
        #pragma unroll
        for (int nt = 0; nt < 8; ++nt) {
            short8 b = *(const short8*)&w1sT[(size_t)(c0 + nt * 16 + m) * 128 + ks * 32 + quad * 8];
            acc[0][nt] = __builtin_amdgcn_mfma_f32_16x16x32_bf16(a0, b, acc[0][nt], 0, 0, 0);
            acc[1][nt] = __builtin_amdgcn_mfma_f32_16x16x32_bf16(a1, b, acc[1][nt], 0, 0, 0);
        }
    }

    // fixup + bf16 into LDS
    const float* w128 = w1s_W + (size_t)128 * 4096;
    float wc[8], bc[8], us[2][4];
    #pragma unroll
    for (int nt = 0; nt < 8; ++nt) {
        wc[nt] = w128[c0 + nt * 16 + m];
        bc[nt] = w1s_b[c0 + nt * 16 + m];
    }
    #pragma unroll
    for (int mt = 0; mt < 2; ++mt)
        #pragma unroll
        for (int reg = 0; reg < 4; ++reg)
            us[mt][reg] = uncertainty[r0 + wave * 32 + mt * 16 + quad * 4 + reg];

    #pragma unroll
    for (int mt = 0; mt < 2; ++mt)
        #pragma unroll
        for (int nt = 0; nt < 8; ++nt) {
            const int row_l = wave * 32 + mt * 16 + quad * 4, c_l = nt * 16 + m;
            #pragma unroll
            for (int reg = 0; reg < 4; ++reg)
                Cs[(row_l + reg) * 136 + c_l] =
                    f2bf(acc[mt][nt][reg] + us[mt][reg] * wc[nt] + bc[nt]);
        }
    __syncthreads();

    #pragma unroll
    for (int t = 0; t < 8; ++t) {
        int i = t * 256 + tid;
        int row = i >> 4, seg = i & 15;
        *(ushort8*)&w1state_bf[(size_t)(r0 + row) * 4096 + c0 + seg * 8] =
            *(const ushort8*)&Cs[row * 136 + seg * 8];
    }
}

// ---------------------------------------------------------------------------
// K2b: per (row, head): Z[e,n] = sum_d W[e,d] g[n,d] via 2 MFMAs; accumulate
// qs[n]*|Z| over h in regs; shfl-reduce n; fold b1/elu/wf/v -> out[row].
// one wave per row. grid 1024 x 256. No LDS.
// ---------------------------------------------------------------------------
__global__ __launch_bounds__(256) void k2b_contract(
    const unsigned short* __restrict__ w1state_bf, // [4096][4096]
    const unsigned short* __restrict__ g_bf,       // [4096][2048]
    const float* __restrict__ agent_qs,            // [4096][16]
    const float* __restrict__ b1v, const float* __restrict__ wfv,
    const float* __restrict__ vv,
    float* __restrict__ out)
{
    const int r = blockIdx.x * 4 + (threadIdx.x >> 6);
    const int lane = threadIdx.x & 63, m = lane & 15, quad = lane >> 4;
    const float qs_l = agent_qs[r * 16 + m];
    const unsigned short* Wr = w1state_bf + (size_t)r * 4096;
    const unsigned short* Gr = g_bf + (size_t)r * 2048;

    float S[2][4] = {};
    #pragma unroll
    for (int h = 0; h < 4; ++h) {
        short8 bfrag = *(const short8*)&Gr[h * 512 + m * 32 + quad * 8];
        #pragma unroll
        for (int t = 0; t < 2; ++t) {
            short8 afrag = *(const short8*)&Wr[h * 1024 + (t * 16 + m) * 32 + quad * 8];
            float4v c = (float4v){0.f, 0.f, 0.f, 0.f};
            c = __builtin_amdgcn_mfma_f32_16x16x32_bf16(afrag, bfrag, c, 0, 0, 0);
            #pragma unroll
            for (int reg = 0; reg < 4; ++reg)
                S[t][reg] = fmaf(fabsf(c[reg]), qs_l, S[t][reg]);
        }
    }
    // reduce over n (lane bits 0..3)
    #pragma unroll
    for (int t = 0; t < 2; ++t)
        #pragma unroll
        for (int reg = 0; reg < 4; ++reg) {
            float v = S[t][reg];
            v += __shfl_xor(v, 1); v += __shfl_xor(v, 2);
            v += __shfl_xor(v, 4); v += __shfl_xor(v, 8);
            S[t][reg] = v;
        }
    float local = 0.f;
    #pragma unroll
    for (int t = 0; t < 2; ++t)
        #pragma unroll
        for (int reg = 0; reg < 4; ++reg) {
            const int e = t * 16 + quad * 4 + reg;
            float hid = 0.25f * S[t][reg] + b1v[r * 32 + e];
            hid = (hid > 0.f) ? hid : expm1f(hid);
            local = fmaf(hid, wfv[r * 32 + e], local);
        }
    local += __shfl_xor(local, 16);
    local += __shfl_xor(local, 32);
    if (lane == 0) out[r] = local + vv[r];
}

// ---------------------------------------------------------------------------
extern "C" void kernel_launch(void* const* d_in, const int* in_sizes, int n_in,
                              void* d_out, int out_size, void* d_ws, size_t ws_size,
                              hipStream_t stream)
{
    const float* agent_qs      = (const float*)d_in[0];
    const float* states        = (const float*)d_in[1];
    const float* hidden_states = (const float*)d_in[2];
    const float* uncertainty   = (const float*)d_in[3];
    const float* W_gat         = (const float*)d_in[4];
    const float* att_a         = (const float*)d_in[5];
    const float* w1s_W         = (const float*)d_in[6];
    const float* w1s_b         = (const float*)d_in[7];
    const float* b1_W          = (const float*)d_in[8];
    const float* b1_b          = (const float*)d_in[9];
    const float* wf_W          = (const float*)d_in[10];
    const float* wf_b          = (const float*)d_in[11];
    const float* V1_W          = (const float*)d_in[12];
    const float* V1_b          = (const float*)d_in[13];
    const float* V2_W          = (const float*)d_in[14];
    const float* V2_b          = (const float*)d_in[15];

    char* w = (char*)d_ws;
    unsigned short* hs_bf   = (unsigned short*)w;  w += (size_t)4194304 * 2;
    unsigned short* A_bf    = (unsigned short*)w;  w += (size_t)524288 * 2;
    unsigned short* w1sT    = (unsigned short*)w;  w += (size_t)524288 * 2;
    unsigned short* WgT     = (unsigned short*)w;  w += (size_t)8192 * 2;
    unsigned short* g_bf    = (unsigned short*)w;  w += (size_t)8388608 * 2;
    unsigned short* w1state = (unsigned short*)w;  w += (size_t)16777216 * 2;
    float* b1v              = (float*)w;           w += (size_t)131072 * 4;
    float* wfv              = (float*)w;           w += (size_t)131072 * 4;
    float* vv               = (float*)w;           w += (size_t)4096 * 4;
    float* out              = (float*)d_out;

    k0a_transpose<<<65, 256, 0, stream>>>(w1s_W, W_gat, w1sT, WgT);
    k0b_convert<<<2304, 256, 0, stream>>>(hidden_states, states, hs_bf, A_bf);

    k1_gat<<<1024, 256, 0, stream>>>(hs_bf, WgT, states, att_a,
        b1_W, b1_b, wf_W, wf_b, V1_W, V1_b, V2_W, V2_b, g_bf, b1v, wfv, vv);

    dim3 grid2(32, 32);
    k2a_gemm<<<grid2, 256, 0, stream>>>(A_bf, w1sT, uncertainty, w1s_W, w1s_b, w1state);

    k2b_contract<<<1024, 256, 0, stream>>>(w1state, g_bf, agent_qs, b1v, wfv, vv, out);
}

// Round 4
// 181.835 us; speedup vs baseline: 1.1559x; 1.1559x over previous
//
#include <hip/hip_runtime.h>
#include <math.h>

// N_AGENTS=16, RNN_H=64, N_HEADS=4, GAT_D=32, EMB=32, SDIM=128, B=4096 rows

typedef __attribute__((ext_vector_type(8))) short short8;
typedef __attribute__((ext_vector_type(8))) unsigned short ushort8;
typedef __attribute__((ext_vector_type(4))) float float4v;

static __device__ inline unsigned short f2bf(float f) {
    unsigned int x;
    __builtin_memcpy(&x, &f, 4);
    unsigned int r = x + 0x7fffu + ((x >> 16) & 1u);   // RNE
    return (unsigned short)(r >> 16);
}

static __device__ inline short8 pack8(float4 f0, float4 f1) {
    ushort8 o;
    o[0] = f2bf(f0.x); o[1] = f2bf(f0.y); o[2] = f2bf(f0.z); o[3] = f2bf(f0.w);
    o[4] = f2bf(f1.x); o[5] = f2bf(f1.y); o[6] = f2bf(f1.z); o[7] = f2bf(f1.w);
    short8 s;
    __builtin_memcpy(&s, &o, 16);
    return s;
}

// ---------------------------------------------------------------------------
// K0: prep. blocks 0..255: w1sT 16-col transpose tiles; 256: WgT; 257..512:
// states -> A_bf. Wide grid so the whole GPU participates.
// ---------------------------------------------------------------------------
__global__ __launch_bounds__(256) void k0_prep(
    const float* __restrict__ w1s_W,     // [129][4096]
    const float* __restrict__ W_gat,     // [64][128]
    const float* __restrict__ states,    // [4096][128]
    unsigned short* __restrict__ w1sT,   // [4096 cols][128 k] bf16
    unsigned short* __restrict__ WgT,    // [128 cols][64 k] bf16
    unsigned short* __restrict__ A_bf)   // [4096][128] bf16
{
    __shared__ __align__(16) unsigned short T[128 * 72];  // 18KB, reused
    const int tid = threadIdx.x, bx = blockIdx.x;
    if (bx < 256) {
        const int c0 = bx * 16;
        const int cc = tid & 15, kr = tid >> 4;
        #pragma unroll
        for (int t = 0; t < 8; ++t) {
            int k = t * 16 + kr;
            T[cc * 136 + k] = f2bf(w1s_W[(size_t)k * 4096 + c0 + cc]);
        }
        __syncthreads();
        const int col = tid >> 4, seg = tid & 15;
        *(ushort8*)&w1sT[(size_t)(c0 + col) * 128 + seg * 8] =
            *(const ushort8*)&T[col * 136 + seg * 8];
    } else if (bx == 256) {
        #pragma unroll
        for (int t = 0; t < 32; ++t) {
            int i = t * 256 + tid;
            int k = i >> 7, c = i & 127;
            T[c * 72 + k] = f2bf(W_gat[k * 128 + c]);
        }
        __syncthreads();
        #pragma unroll
        for (int t = 0; t < 4; ++t) {
            int i = t * 256 + tid;
            int c = i >> 3, seg = i & 7;
            *(ushort8*)&WgT[c * 64 + seg * 8] = *(const ushort8*)&T[c * 72 + seg * 8];
        }
    } else {
        int u = (bx - 257) * 256 + tid;            // < 65536 units of 8 elems
        const float* src = states + (size_t)u * 8;
        float4 f0 = *(const float4*)src;
        float4 f1 = *(const float4*)(src + 4);
        short8 s = pack8(f0, f1);
        *(short8*)&A_bf[(size_t)u * 8] = s;
    }
}

// ---------------------------------------------------------------------------
// K1: GAT. 2 batch rows/block, 128 threads, grid 2048.
// Phase A: hp via MFMA (hs fp32 converted in-flight; WgT frags from global).
// Phase B: attention softmax, attn -> LDS.
// Phase C: g-einsum, 8 d's/thread, wave-uniform h (conflict-free hp reads).
// Phase D: small GEMVs.
// hp LDS: [row*164 + h*40 + d] (16B-aligned offsets, banks spread).
// ---------------------------------------------------------------------------
__global__ __launch_bounds__(128) void k1_gat(
    const float* __restrict__ hidden_states,  // [4096*16][64] fp32
    const unsigned short* __restrict__ WgT,   // [128][64] bf16
    const float* __restrict__ states,
    const float* __restrict__ att_a,
    const float* __restrict__ b1_W, const float* __restrict__ b1_b,
    const float* __restrict__ wf_W, const float* __restrict__ wf_b,
    const float* __restrict__ V1_W, const float* __restrict__ V1_b,
    const float* __restrict__ V2_W, const float* __restrict__ V2_b,
    unsigned short* __restrict__ g_bf,        // [B][4][16][32] bf16
    float* __restrict__ b1v, float* __restrict__ wfv, float* __restrict__ vv)
{
    const int b0 = blockIdx.x * 2, tid = threadIdx.x;
    const int wave = tid >> 6, lane = tid & 63, m = lane & 15, quad = lane >> 4;
    __shared__ __align__(16) float hp[32 * 164];   // 21.0 KB
    __shared__ float attn[8 * 272];                // [(bb*4+h)][i*17+j]  8.7 KB
    __shared__ float dstv[2 * 68];
    __shared__ float red[64];

    // ---- Phase A: hp[32 rows][128 cols] via MFMA; wave = batch row ----
    {
        const float* hrow = hidden_states + ((size_t)(b0 + wave) * 16 + m) * 64;
        float4 f0 = *(const float4*)(hrow + quad * 8);
        float4 f1 = *(const float4*)(hrow + quad * 8 + 4);
        short8 a0 = pack8(f0, f1);
        f0 = *(const float4*)(hrow + 32 + quad * 8);
        f1 = *(const float4*)(hrow + 32 + quad * 8 + 4);
        short8 a1 = pack8(f0, f1);

        float4v acc[8];
        #pragma unroll
        for (int nt = 0; nt < 8; ++nt) acc[nt] = (float4v){0.f, 0.f, 0.f, 0.f};
        #pragma unroll
        for (int nt = 0; nt < 8; ++nt) {
            const int c = nt * 16 + m;
            short8 bf0 = *(const short8*)&WgT[c * 64 + quad * 8];
            short8 bf1 = *(const short8*)&WgT[c * 64 + 32 + quad * 8];
            acc[nt] = __builtin_amdgcn_mfma_f32_16x16x32_bf16(a0, bf0, acc[nt], 0, 0, 0);
            acc[nt] = __builtin_amdgcn_mfma_f32_16x16x32_bf16(a1, bf1, acc[nt], 0, 0, 0);
        }
        #pragma unroll
        for (int nt = 0; nt < 8; ++nt) {
            const int c = nt * 16 + m, h = c >> 5, d = c & 31;
            #pragma unroll
            for (int reg = 0; reg < 4; ++reg)
                hp[(wave * 16 + quad * 4 + reg) * 164 + h * 40 + d] = acc[nt][reg];
        }
    }
    __syncthreads();

    // ---- Phase B: attention; thread = (bb = tid>>6, h = (tid>>4)&3, i = tid&15)
    {
        const int bb = tid >> 6, h = (tid >> 4) & 3, ii = tid & 15;
        const float* hrow = &hp[(bb * 16 + ii) * 164 + h * 40];
        float src = 0.f, dst = 0.f;
        #pragma unroll
        for (int s = 0; s < 8; ++s) {
            float4 v  = *(const float4*)&hrow[s * 4];
            float4 as = *(const float4*)&att_a[h * 64 + s * 4];
            float4 ad = *(const float4*)&att_a[h * 64 + 32 + s * 4];
            src += v.x * as.x + v.y * as.y + v.z * as.z + v.w * as.w;
            dst += v.x * ad.x + v.y * ad.y + v.z * ad.z + v.w * ad.w;
        }
        dstv[bb * 68 + h * 17 + ii] = dst;
        __syncthreads();

        float ev[16], mx = -1e30f;
        #pragma unroll
        for (int j = 0; j < 16; ++j) {
            float x = src + dstv[bb * 68 + h * 17 + j];
            x = (x >= 0.f) ? x : 0.2f * x;
            ev[j] = x; mx = fmaxf(mx, x);
        }
        float ssum = 0.f;
        #pragma unroll
        for (int j = 0; j < 16; ++j) { float p = expf(ev[j] - mx); ev[j] = p; ssum += p; }
        const float inv = 1.f / ssum;
        #pragma unroll
        for (int j = 0; j < 16; ++j)
            attn[(bb * 4 + h) * 272 + ii * 17 + j] = ev[j] * inv;
    }
    __syncthreads();

    // ---- Phase C: g-einsum. it covers (bb, h-pair); h = (it&1)*2 + wave ----
    #pragma unroll
    for (int it = 0; it < 4; ++it) {
        const int bb = it >> 1, h = ((it & 1) << 1) | wave;
        const int i2 = (tid >> 2) & 15, dq = tid & 3;
        const float* ar = &attn[(bb * 4 + h) * 272 + i2 * 17];
        float acc[8] = {};
        #pragma unroll
        for (int j = 0; j < 16; ++j) {
            const float p = ar[j];
            const float* hj = &hp[(bb * 16 + j) * 164 + h * 40 + dq * 8];
            float4 v0 = *(const float4*)hj;
            float4 v1 = *(const float4*)(hj + 4);
            acc[0] = fmaf(p, v0.x, acc[0]); acc[1] = fmaf(p, v0.y, acc[1]);
            acc[2] = fmaf(p, v0.z, acc[2]); acc[3] = fmaf(p, v0.w, acc[3]);
            acc[4] = fmaf(p, v1.x, acc[4]); acc[5] = fmaf(p, v1.y, acc[5]);
            acc[6] = fmaf(p, v1.z, acc[6]); acc[7] = fmaf(p, v1.w, acc[7]);
        }
        ushort8 o;
        #pragma unroll
        for (int t = 0; t < 8; ++t) {
            float x = acc[t];
            x = (x > 0.f) ? x : expm1f(x);
            o[t] = f2bf(x);
        }
        *(ushort8*)&g_bf[((size_t)(b0 + bb) * 4 + h) * 512 + i2 * 32 + dq * 8] = o;
    }

    // ---- Phase D: small GEMVs: 192 items: (bbx = grp&1, which = grp>>1, e) ----
    for (int p = tid; p < 192; p += 128) {
        const int e = p & 31, grp = p >> 5, bbx = grp & 1, which = grp >> 1;
        const float* Wm = (which == 0) ? b1_W : ((which == 1) ? wf_W : V1_W);
        const float* sr = states + (size_t)(b0 + bbx) * 128;
        float acc = 0.f;
        #pragma unroll 8
        for (int k = 0; k < 128; ++k) acc = fmaf(sr[k], Wm[k * 32 + e], acc);
        const int r = (b0 + bbx) * 32 + e;
        if (which == 0)      b1v[r] = acc + b1_b[e];
        else if (which == 1) wfv[r] = fabsf(acc + wf_b[e]);
        else                 red[bbx * 32 + e] = fmaxf(acc + V1_b[e], 0.f) * V2_W[e];
    }
    __syncthreads();
    if (tid < 2) {
        float acc = V2_b[0];
        #pragma unroll
        for (int e = 0; e < 32; ++e) acc += red[tid * 32 + e];
        vv[b0 + tid] = acc;
    }
}

// ---------------------------------------------------------------------------
// K2a: w1state_bf = bf16( s_aug @ w1s_W + b ) via MFMA, K=128 + fp32 fixup
// for k=128 (uncertainty). 128x128 tile; frags direct from global (L2-hot);
// LDS only as store-stage. grid (32,32).
// ---------------------------------------------------------------------------
__global__ __launch_bounds__(256) void k2a_gemm(
    const unsigned short* __restrict__ A_bf,    // [4096][128]
    const unsigned short* __restrict__ w1sT,    // [4096][128]
    const float* __restrict__ uncertainty,      // [4096]
    const float* __restrict__ w1s_W,            // row 128
    const float* __restrict__ w1s_b,
    unsigned short* __restrict__ w1state_bf)    // [4096][4096]
{
    const int r0 = blockIdx.x * 128, c0 = blockIdx.y * 128;
    const int tid = threadIdx.x;
    const int wave = tid >> 6, lane = tid & 63, m = lane & 15, quad = lane >> 4;
    __shared__ __align__(16) unsigned short Cs[128 * 136];

    float4v acc[2][8];
    #pragma unroll
    for (int mt = 0; mt < 2; ++mt)
        #pragma unroll
        for (int nt = 0; nt < 8; ++nt) acc[mt][nt] = (float4v){0.f, 0.f, 0.f, 0.f};

    #pragma unroll
    for (int ks = 0; ks < 4; ++ks) {
        short8 a0 = *(const short8*)&A_bf[(size_t)(r0 + wave * 32 + m) * 128 + ks * 32 + quad * 8];
        short8 a1 = *(const short8*)&A_bf[(size_t)(r0 + wave * 32 + 16 + m) * 128 + ks * 32 + quad * 8];
        #pragma unroll
        for (int nt = 0; nt < 8; ++nt) {
            short8 b = *(const short8*)&w1sT[(size_t)(c0 + nt * 16 + m) * 128 + ks * 32 + quad * 8];
            acc[0][nt] = __builtin_amdgcn_mfma_f32_16x16x32_bf16(a0, b, acc[0][nt], 0, 0, 0);
            acc[1][nt] = __builtin_amdgcn_mfma_f32_16x16x32_bf16(a1, b, acc[1][nt], 0, 0, 0);
        }
    }

    const float* w128 = w1s_W + (size_t)128 * 4096;
    float wc[8], bc[8], us[2][4];
    #pragma unroll
    for (int nt = 0; nt < 8; ++nt) {
        wc[nt] = w128[c0 + nt * 16 + m];
        bc[nt] = w1s_b[c0 + nt * 16 + m];
    }
    #pragma unroll
    for (int mt = 0; mt < 2; ++mt)
        #pragma unroll
        for (int reg = 0; reg < 4; ++reg)
            us[mt][reg] = uncertainty[r0 + wave * 32 + mt * 16 + quad * 4 + reg];

    #pragma unroll
    for (int mt = 0; mt < 2; ++mt)
        #pragma unroll
        for (int nt = 0; nt < 8; ++nt) {
            const int row_l = wave * 32 + mt * 16 + quad * 4, c_l = nt * 16 + m;
            #pragma unroll
            for (int reg = 0; reg < 4; ++reg)
                Cs[(row_l + reg) * 136 + c_l] =
                    f2bf(acc[mt][nt][reg] + us[mt][reg] * wc[nt] + bc[nt]);
        }
    __syncthreads();

    #pragma unroll
    for (int t = 0; t < 8; ++t) {
        int i = t * 256 + tid;
        int row = i >> 4, seg = i & 15;
        *(ushort8*)&w1state_bf[(size_t)(r0 + row) * 4096 + c0 + seg * 8] =
            *(const ushort8*)&Cs[row * 136 + seg * 8];
    }
}

// ---------------------------------------------------------------------------
// K2b: per (row, head): Z[e,n] = sum_d W[e,d] g[n,d] via 2 MFMAs; accumulate
// qs[n]*|Z| over h in regs; shfl-reduce n; fold b1/elu/wf/v -> out[row].
// one wave per row. grid 1024 x 256. No LDS.
// ---------------------------------------------------------------------------
__global__ __launch_bounds__(256) void k2b_contract(
    const unsigned short* __restrict__ w1state_bf, // [4096][4096]
    const unsigned short* __restrict__ g_bf,       // [4096][2048]
    const float* __restrict__ agent_qs,            // [4096][16]
    const float* __restrict__ b1v, const float* __restrict__ wfv,
    const float* __restrict__ vv,
    float* __restrict__ out)
{
    const int r = blockIdx.x * 4 + (threadIdx.x >> 6);
    const int lane = threadIdx.x & 63, m = lane & 15, quad = lane >> 4;
    const float qs_l = agent_qs[r * 16 + m];
    const unsigned short* Wr = w1state_bf + (size_t)r * 4096;
    const unsigned short* Gr = g_bf + (size_t)r * 2048;

    float S[2][4] = {};
    #pragma unroll
    for (int h = 0; h < 4; ++h) {
        short8 bfrag = *(const short8*)&Gr[h * 512 + m * 32 + quad * 8];
        #pragma unroll
        for (int t = 0; t < 2; ++t) {
            short8 afrag = *(const short8*)&Wr[h * 1024 + (t * 16 + m) * 32 + quad * 8];
            float4v c = (float4v){0.f, 0.f, 0.f, 0.f};
            c = __builtin_amdgcn_mfma_f32_16x16x32_bf16(afrag, bfrag, c, 0, 0, 0);
            #pragma unroll
            for (int reg = 0; reg < 4; ++reg)
                S[t][reg] = fmaf(fabsf(c[reg]), qs_l, S[t][reg]);
        }
    }
    #pragma unroll
    for (int t = 0; t < 2; ++t)
        #pragma unroll
        for (int reg = 0; reg < 4; ++reg) {
            float v = S[t][reg];
            v += __shfl_xor(v, 1); v += __shfl_xor(v, 2);
            v += __shfl_xor(v, 4); v += __shfl_xor(v, 8);
            S[t][reg] = v;
        }
    float local = 0.f;
    #pragma unroll
    for (int t = 0; t < 2; ++t)
        #pragma unroll
        for (int reg = 0; reg < 4; ++reg) {
            const int e = t * 16 + quad * 4 + reg;
            float hid = 0.25f * S[t][reg] + b1v[r * 32 + e];
            hid = (hid > 0.f) ? hid : expm1f(hid);
            local = fmaf(hid, wfv[r * 32 + e], local);
        }
    local += __shfl_xor(local, 16);
    local += __shfl_xor(local, 32);
    if (lane == 0) out[r] = local + vv[r];
}

// ---------------------------------------------------------------------------
extern "C" void kernel_launch(void* const* d_in, const int* in_sizes, int n_in,
                              void* d_out, int out_size, void* d_ws, size_t ws_size,
                              hipStream_t stream)
{
    const float* agent_qs      = (const float*)d_in[0];
    const float* states        = (const float*)d_in[1];
    const float* hidden_states = (const float*)d_in[2];
    const float* uncertainty   = (const float*)d_in[3];
    const float* W_gat         = (const float*)d_in[4];
    const float* att_a         = (const float*)d_in[5];
    const float* w1s_W         = (const float*)d_in[6];
    const float* w1s_b         = (const float*)d_in[7];
    const float* b1_W          = (const float*)d_in[8];
    const float* b1_b          = (const float*)d_in[9];
    const float* wf_W          = (const float*)d_in[10];
    const float* wf_b          = (const float*)d_in[11];
    const float* V1_W          = (const float*)d_in[12];
    const float* V1_b          = (const float*)d_in[13];
    const float* V2_W          = (const float*)d_in[14];
    const float* V2_b          = (const float*)d_in[15];

    char* w = (char*)d_ws;
    unsigned short* w1sT    = (unsigned short*)w;  w += (size_t)524288 * 2;
    unsigned short* WgT     = (unsigned short*)w;  w += (size_t)8192 * 2;
    unsigned short* A_bf    = (unsigned short*)w;  w += (size_t)524288 * 2;
    unsigned short* g_bf    = (unsigned short*)w;  w += (size_t)8388608 * 2;
    unsigned short* w1state = (unsigned short*)w;  w += (size_t)16777216 * 2;
    float* b1v              = (float*)w;           w += (size_t)131072 * 4;
    float* wfv              = (float*)w;           w += (size_t)131072 * 4;
    float* vv               = (float*)w;           w += (size_t)4096 * 4;
    float* out              = (float*)d_out;

    k0_prep<<<513, 256, 0, stream>>>(w1s_W, W_gat, states, w1sT, WgT, A_bf);

    k1_gat<<<2048, 128, 0, stream>>>(hidden_states, WgT, states, att_a,
        b1_W, b1_b, wf_W, wf_b, V1_W, V1_b, V2_W, V2_b, g_bf, b1v, wfv, vv);

    dim3 grid2(32, 32);
    k2a_gemm<<<grid2, 256, 0, stream>>>(A_bf, w1sT, uncertainty, w1s_W, w1s_b, w1state);

    k2b_contract<<<1024, 256, 0, stream>>>(w1state, g_bf, agent_qs, b1v, wfv, vv, out);
}

// Round 5
// 180.657 us; speedup vs baseline: 1.1635x; 1.0065x over previous
//
#include <hip/hip_runtime.h>
#include <math.h>

// N_AGENTS=16, RNN_H=64, N_HEADS=4, GAT_D=32, EMB=32, SDIM=128, B=4096 rows

typedef __attribute__((ext_vector_type(8))) short short8;
typedef __attribute__((ext_vector_type(8))) unsigned short ushort8;
typedef __attribute__((ext_vector_type(4))) unsigned short ushort4v;
typedef __attribute__((ext_vector_type(4))) float float4v;
typedef __attribute__((ext_vector_type(4))) _Float16 half4v;

static __device__ inline unsigned short f2bf(float f) {
    unsigned int x;
    __builtin_memcpy(&x, &f, 4);
    unsigned int r = x + 0x7fffu + ((x >> 16) & 1u);   // RNE
    return (unsigned short)(r >> 16);
}

static __device__ inline short8 pack8(float4 f0, float4 f1) {
    ushort8 o;
    o[0] = f2bf(f0.x); o[1] = f2bf(f0.y); o[2] = f2bf(f0.z); o[3] = f2bf(f0.w);
    o[4] = f2bf(f1.x); o[5] = f2bf(f1.y); o[6] = f2bf(f1.z); o[7] = f2bf(f1.w);
    short8 s;
    __builtin_memcpy(&s, &o, 16);
    return s;
}

// ---------------------------------------------------------------------------
// K0: prep. blocks 0..255: w1sT 16-col transpose tiles; 256: WgT; 257: WsT
// (small-GEMV weights transposed, fp32); 258..513: states -> A_bf.
// ---------------------------------------------------------------------------
__global__ __launch_bounds__(256) void k0_prep(
    const float* __restrict__ w1s_W,     // [129][4096]
    const float* __restrict__ W_gat,     // [64][128]
    const float* __restrict__ states,    // [4096][128]
    const float* __restrict__ b1_W,      // [128][32]
    const float* __restrict__ wf_W,      // [128][32]
    const float* __restrict__ V1_W,      // [128][32]
    unsigned short* __restrict__ w1sT,   // [4096 cols][128 k] bf16
    unsigned short* __restrict__ WgT,    // [128 cols][64 k] bf16
    float* __restrict__ WsT,             // [96][128] fp32 (b1|wf|V1 transposed)
    unsigned short* __restrict__ A_bf)   // [4096][128] bf16
{
    __shared__ __align__(16) unsigned short T[128 * 72];  // 18KB, reused
    const int tid = threadIdx.x, bx = blockIdx.x;
    if (bx < 256) {
        const int c0 = bx * 16;
        const int cc = tid & 15, kr = tid >> 4;
        #pragma unroll
        for (int t = 0; t < 8; ++t) {
            int k = t * 16 + kr;
            T[cc * 136 + k] = f2bf(w1s_W[(size_t)k * 4096 + c0 + cc]);
        }
        __syncthreads();
        const int col = tid >> 4, seg = tid & 15;
        *(ushort8*)&w1sT[(size_t)(c0 + col) * 128 + seg * 8] =
            *(const ushort8*)&T[col * 136 + seg * 8];
    } else if (bx == 256) {
        #pragma unroll
        for (int t = 0; t < 32; ++t) {
            int i = t * 256 + tid;
            int k = i >> 7, c = i & 127;
            T[c * 72 + k] = f2bf(W_gat[k * 128 + c]);
        }
        __syncthreads();
        #pragma unroll
        for (int t = 0; t < 4; ++t) {
            int i = t * 256 + tid;
            int c = i >> 3, seg = i & 7;
            *(ushort8*)&WgT[c * 64 + seg * 8] = *(const ushort8*)&T[c * 72 + seg * 8];
        }
    } else if (bx == 257) {
        // WsT[set*32+e][k] = Wm[k][e], fp32, 96x128
        for (int i = tid; i < 12288; i += 256) {
            int row = i >> 7, k = i & 127;
            int set = row >> 5, e = row & 31;
            const float* Wm = (set == 0) ? b1_W : ((set == 1) ? wf_W : V1_W);
            WsT[(size_t)row * 128 + k] = Wm[k * 32 + e];
        }
    } else {
        int u = (bx - 258) * 256 + tid;            // < 65536 units of 8 elems
        const float* src = states + (size_t)u * 8;
        float4 f0 = *(const float4*)src;
        float4 f1 = *(const float4*)(src + 4);
        short8 s = pack8(f0, f1);
        *(short8*)&A_bf[(size_t)u * 8] = s;
    }
}

// ---------------------------------------------------------------------------
// K1: GAT, fully wave-local: 1 wave = 1 batch row. NO LDS, NO barriers.
//  MFMA1 (16x16x32 bf16): hp[16 agents][128] -> accumulators (C-layout).
//  Attention: cross-lane shuffle reductions + per-lane softmax (4 j's/lane).
//  MFMA2 (16x16x16 f16): g = attn-weighted hp. Key identity: MFMA1's C-frag
//  IS MFMA2's A-frag for the transposed product (lane m=d', k=quad*4+t),
//  and the per-lane attn values are exactly MFMA2's B-frag (lane m=i).
//  Then small GEMVs vs pre-transposed WsT.
// ---------------------------------------------------------------------------
__global__ __launch_bounds__(256) void k1_gat(
    const float* __restrict__ hidden_states,  // [4096*16][64] fp32
    const unsigned short* __restrict__ WgT,   // [128][64] bf16
    const float* __restrict__ states,
    const float* __restrict__ att_a,
    const float* __restrict__ WsT,            // [96][128] fp32
    const float* __restrict__ b1_b, const float* __restrict__ wf_b,
    const float* __restrict__ V1_b, const float* __restrict__ V2_W,
    const float* __restrict__ V2_b,
    unsigned short* __restrict__ g_bf,        // [B][4][16][32] bf16
    float* __restrict__ b1v, float* __restrict__ wfv, float* __restrict__ vv)
{
    const int b = blockIdx.x * 4 + (threadIdx.x >> 6);
    const int lane = threadIdx.x & 63, m = lane & 15, quad = lane >> 4;

    // ---- MFMA1: hp tiles; hpt[nt] lane holds hp[quad*4+t][nt*16+m] ----
    const float* hrow = hidden_states + ((size_t)b * 16 + m) * 64;
    float4 f0 = *(const float4*)(hrow + quad * 8);
    float4 f1 = *(const float4*)(hrow + quad * 8 + 4);
    short8 a0 = pack8(f0, f1);
    f0 = *(const float4*)(hrow + 32 + quad * 8);
    f1 = *(const float4*)(hrow + 32 + quad * 8 + 4);
    short8 a1 = pack8(f0, f1);

    float4v hpt[8];
    #pragma unroll
    for (int nt = 0; nt < 8; ++nt) {
        const int c = nt * 16 + m;
        short8 bf0 = *(const short8*)&WgT[c * 64 + quad * 8];
        short8 bf1 = *(const short8*)&WgT[c * 64 + 32 + quad * 8];
        float4v z = (float4v){0.f, 0.f, 0.f, 0.f};
        z = __builtin_amdgcn_mfma_f32_16x16x32_bf16(a0, bf0, z, 0, 0, 0);
        z = __builtin_amdgcn_mfma_f32_16x16x32_bf16(a1, bf1, z, 0, 0, 0);
        hpt[nt] = z;
    }

    // ---- per head: attention + MFMA2 ----
    #pragma unroll
    for (int h = 0; h < 4; ++h) {
        float4v t0 = hpt[2 * h], t1 = hpt[2 * h + 1];
        // head-h cols: tile 2h -> d=m, tile 2h+1 -> d=16+m
        float as0 = att_a[h * 64 + m],      as1 = att_a[h * 64 + 16 + m];
        float ad0 = att_a[h * 64 + 32 + m], ad1 = att_a[h * 64 + 48 + m];
        float ps[4], pd[4];
        #pragma unroll
        for (int r = 0; r < 4; ++r) {
            ps[r] = t0[r] * as0 + t1[r] * as1;
            pd[r] = t0[r] * ad0 + t1[r] * ad1;
        }
        // reduce over d (lane bits 0..3): ps[r] -> src[i=quad*4+r], pd -> dst
        #pragma unroll
        for (int mask = 1; mask <= 8; mask <<= 1) {
            #pragma unroll
            for (int r = 0; r < 4; ++r) {
                ps[r] += __shfl_xor(ps[r], mask);
                pd[r] += __shfl_xor(pd[r], mask);
            }
        }
        // gather src[i=m] to this lane (value lives at quad-group m>>2, reg m&3)
        const int srcLane = (m >> 2) << 4;
        float s0 = __shfl(ps[0], srcLane), s1 = __shfl(ps[1], srcLane);
        float s2 = __shfl(ps[2], srcLane), s3 = __shfl(ps[3], srcLane);
        const int sel = m & 3;
        float src_m = (sel == 0) ? s0 : (sel == 1) ? s1 : (sel == 2) ? s2 : s3;

        // softmax over j for row i=m; this lane owns j = quad*4+jj (dst = pd)
        float e_[4];
        #pragma unroll
        for (int jj = 0; jj < 4; ++jj) {
            float x = src_m + pd[jj];
            e_[jj] = fmaxf(x, 0.2f * x);       // leaky_relu(0.2)
        }
        float mx = fmaxf(fmaxf(e_[0], e_[1]), fmaxf(e_[2], e_[3]));
        mx = fmaxf(mx, __shfl_xor(mx, 16));
        mx = fmaxf(mx, __shfl_xor(mx, 32));
        float p_[4], ssum = 0.f;
        #pragma unroll
        for (int jj = 0; jj < 4; ++jj) { p_[jj] = __expf(e_[jj] - mx); ssum += p_[jj]; }
        ssum += __shfl_xor(ssum, 16);
        ssum += __shfl_xor(ssum, 32);
        const float inv = __builtin_amdgcn_rcpf(ssum);

        half4v bfrag;   // B[k=j=quad*4+jj][n=i=m] = attn[i][j]
        #pragma unroll
        for (int jj = 0; jj < 4; ++jj) bfrag[jj] = (_Float16)(p_[jj] * inv);

        #pragma unroll
        for (int p = 0; p < 2; ++p) {
            // A[m=d'][k=j=quad*4+t] = hp[quad*4+t][h*32+p*16+m] == hpt[2h+p]
            float4v ct = hpt[2 * h + p];
            half4v afrag;
            #pragma unroll
            for (int t = 0; t < 4; ++t) afrag[t] = (_Float16)ct[t];
            float4v z = (float4v){0.f, 0.f, 0.f, 0.f};
            z = __builtin_amdgcn_mfma_f32_16x16x16f16(afrag, bfrag, z, 0, 0, 0);
            // D: lane col = i = m, rows d' = quad*4+t  -> g[i][p*16+quad*4+t]
            ushort4v o;
            #pragma unroll
            for (int t = 0; t < 4; ++t) {
                float x = z[t];
                float ex = __expf(x) - 1.f;    // elu
                x = (x > 0.f) ? x : ex;
                o[t] = f2bf(x);
            }
            *(ushort4v*)&g_bf[((size_t)b * 4 + h) * 512 + m * 32 + p * 16 + quad * 4] = o;
        }
    }

    // ---- small GEMVs vs WsT (k-contiguous): lane = (e=lane&31, khalf) ----
    const int e = lane & 31, khalf = lane >> 5;
    const float* srow = states + (size_t)b * 128 + khalf * 64;
    float accs[3];
    #pragma unroll
    for (int set = 0; set < 3; ++set) {
        const float* wrow = WsT + (size_t)(set * 32 + e) * 128 + khalf * 64;
        float a = 0.f;
        #pragma unroll
        for (int kk = 0; kk < 16; ++kk) {
            float4 wv = *(const float4*)(wrow + kk * 4);
            float4 sv = *(const float4*)(srow + kk * 4);
            a += wv.x * sv.x + wv.y * sv.y + wv.z * sv.z + wv.w * sv.w;
        }
        accs[set] = a + __shfl_xor(a, 32);
    }
    if (khalf == 0) {
        b1v[b * 32 + e] = accs[0] + b1_b[e];
        wfv[b * 32 + e] = fabsf(accs[1] + wf_b[e]);
    }
    float r3 = fmaxf(accs[2] + V1_b[e], 0.f) * V2_W[e];
    r3 += __shfl_xor(r3, 1);  r3 += __shfl_xor(r3, 2);
    r3 += __shfl_xor(r3, 4);  r3 += __shfl_xor(r3, 8);
    r3 += __shfl_xor(r3, 16);
    if (lane == 0) vv[b] = r3 + V2_b[0];
}

// ---------------------------------------------------------------------------
// K2a: w1state_bf = bf16( s_aug @ w1s_W + b ) via MFMA, K=128 + fp32 fixup
// for k=128 (uncertainty). 128x128 tile; frags direct from global (L2-hot);
// LDS only as store-stage. grid (32,32).
// ---------------------------------------------------------------------------
__global__ __launch_bounds__(256) void k2a_gemm(
    const unsigned short* __restrict__ A_bf,    // [4096][128]
    const unsigned short* __restrict__ w1sT,    // [4096][128]
    const float* __restrict__ uncertainty,      // [4096]
    const float* __restrict__ w1s_W,            // row 128
    const float* __restrict__ w1s_b,
    unsigned short* __restrict__ w1state_bf)    // [4096][4096]
{
    const int r0 = blockIdx.x * 128, c0 = blockIdx.y * 128;
    const int tid = threadIdx.x;
    const int wave = tid >> 6, lane = tid & 63, m = lane & 15, quad = lane >> 4;
    __shared__ __align__(16) unsigned short Cs[128 * 136];

    float4v acc[2][8];
    #pragma unroll
    for (int mt = 0; mt < 2; ++mt)
        #pragma unroll
        for (int nt = 0; nt < 8; ++nt) acc[mt][nt] = (float4v){0.f, 0.f, 0.f, 0.f};

    #pragma unroll
    for (int ks = 0; ks < 4; ++ks) {
        short8 a0 = *(const short8*)&A_bf[(size_t)(r0 + wave * 32 + m) * 128 + ks * 32 + quad * 8];
        short8 a1 = *(const short8*)&A_bf[(size_t)(r0 + wave * 32 + 16 + m) * 128 + ks * 32 + quad * 8];
        #pragma unroll
        for (int nt = 0; nt < 8; ++nt) {
            short8 b = *(const short8*)&w1sT[(size_t)(c0 + nt * 16 + m) * 128 + ks * 32 + quad * 8];
            acc[0][nt] = __builtin_amdgcn_mfma_f32_16x16x32_bf16(a0, b, acc[0][nt], 0, 0, 0);
            acc[1][nt] = __builtin_amdgcn_mfma_f32_16x16x32_bf16(a1, b, acc[1][nt], 0, 0, 0);
        }
    }

    const float* w128 = w1s_W + (size_t)128 * 4096;
    float wc[8], bc[8], us[2][4];
    #pragma unroll
    for (int nt = 0; nt < 8; ++nt) {
        wc[nt] = w128[c0 + nt * 16 + m];
        bc[nt] = w1s_b[c0 + nt * 16 + m];
    }
    #pragma unroll
    for (int mt = 0; mt < 2; ++mt)
        #pragma unroll
        for (int reg = 0; reg < 4; ++reg)
            us[mt][reg] = uncertainty[r0 + wave * 32 + mt * 16 + quad * 4 + reg];

    #pragma unroll
    for (int mt = 0; mt < 2; ++mt)
        #pragma unroll
        for (int nt = 0; nt < 8; ++nt) {
            const int row_l = wave * 32 + mt * 16 + quad * 4, c_l = nt * 16 + m;
            #pragma unroll
            for (int reg = 0; reg < 4; ++reg)
                Cs[(row_l + reg) * 136 + c_l] =
                    f2bf(acc[mt][nt][reg] + us[mt][reg] * wc[nt] + bc[nt]);
        }
    __syncthreads();

    #pragma unroll
    for (int t = 0; t < 8; ++t) {
        int i = t * 256 + tid;
        int row = i >> 4, seg = i & 15;
        *(ushort8*)&w1state_bf[(size_t)(r0 + row) * 4096 + c0 + seg * 8] =
            *(const ushort8*)&Cs[row * 136 + seg * 8];
    }
}

// ---------------------------------------------------------------------------
// K2b: per (row, head): Z[e,n] = sum_d W[e,d] g[n,d] via 2 MFMAs; accumulate
// qs[n]*|Z| over h in regs; shfl-reduce n; fold b1/elu/wf/v -> out[row].
// one wave per row. grid 1024 x 256. No LDS.
// ---------------------------------------------------------------------------
__global__ __launch_bounds__(256) void k2b_contract(
    const unsigned short* __restrict__ w1state_bf, // [4096][4096]
    const unsigned short* __restrict__ g_bf,       // [4096][2048]
    const float* __restrict__ agent_qs,            // [4096][16]
    const float* __restrict__ b1v, const float* __restrict__ wfv,
    const float* __restrict__ vv,
    float* __restrict__ out)
{
    const int r = blockIdx.x * 4 + (threadIdx.x >> 6);
    const int lane = threadIdx.x & 63, m = lane & 15, quad = lane >> 4;
    const float qs_l = agent_qs[r * 16 + m];
    const unsigned short* Wr = w1state_bf + (size_t)r * 4096;
    const unsigned short* Gr = g_bf + (size_t)r * 2048;

    float S[2][4] = {};
    #pragma unroll
    for (int h = 0; h < 4; ++h) {
        short8 bfrag = *(const short8*)&Gr[h * 512 + m * 32 + quad * 8];
        #pragma unroll
        for (int t = 0; t < 2; ++t) {
            short8 afrag = *(const short8*)&Wr[h * 1024 + (t * 16 + m) * 32 + quad * 8];
            float4v c = (float4v){0.f, 0.f, 0.f, 0.f};
            c = __builtin_amdgcn_mfma_f32_16x16x32_bf16(afrag, bfrag, c, 0, 0, 0);
            #pragma unroll
            for (int reg = 0; reg < 4; ++reg)
                S[t][reg] = fmaf(fabsf(c[reg]), qs_l, S[t][reg]);
        }
    }
    #pragma unroll
    for (int t = 0; t < 2; ++t)
        #pragma unroll
        for (int reg = 0; reg < 4; ++reg) {
            float v = S[t][reg];
            v += __shfl_xor(v, 1); v += __shfl_xor(v, 2);
            v += __shfl_xor(v, 4); v += __shfl_xor(v, 8);
            S[t][reg] = v;
        }
    float local = 0.f;
    #pragma unroll
    for (int t = 0; t < 2; ++t)
        #pragma unroll
        for (int reg = 0; reg < 4; ++reg) {
            const int e = t * 16 + quad * 4 + reg;
            float hid = 0.25f * S[t][reg] + b1v[r * 32 + e];
            hid = (hid > 0.f) ? hid : expm1f(hid);
            local = fmaf(hid, wfv[r * 32 + e], local);
        }
    local += __shfl_xor(local, 16);
    local += __shfl_xor(local, 32);
    if (lane == 0) out[r] = local + vv[r];
}

// ---------------------------------------------------------------------------
extern "C" void kernel_launch(void* const* d_in, const int* in_sizes, int n_in,
                              void* d_out, int out_size, void* d_ws, size_t ws_size,
                              hipStream_t stream)
{
    const float* agent_qs      = (const float*)d_in[0];
    const float* states        = (const float*)d_in[1];
    const float* hidden_states = (const float*)d_in[2];
    const float* uncertainty   = (const float*)d_in[3];
    const float* W_gat         = (const float*)d_in[4];
    const float* att_a         = (const float*)d_in[5];
    const float* w1s_W         = (const float*)d_in[6];
    const float* w1s_b         = (const float*)d_in[7];
    const float* b1_W          = (const float*)d_in[8];
    const float* b1_b          = (const float*)d_in[9];
    const float* wf_W          = (const float*)d_in[10];
    const float* wf_b          = (const float*)d_in[11];
    const float* V1_W          = (const float*)d_in[12];
    const float* V1_b          = (const float*)d_in[13];
    const float* V2_W          = (const float*)d_in[14];
    const float* V2_b          = (const float*)d_in[15];

    char* w = (char*)d_ws;
    unsigned short* w1sT    = (unsigned short*)w;  w += (size_t)524288 * 2;
    unsigned short* WgT     = (unsigned short*)w;  w += (size_t)8192 * 2;
    unsigned short* A_bf    = (unsigned short*)w;  w += (size_t)524288 * 2;
    float* WsT              = (float*)w;           w += (size_t)12288 * 4;
    unsigned short* g_bf    = (unsigned short*)w;  w += (size_t)8388608 * 2;
    unsigned short* w1state = (unsigned short*)w;  w += (size_t)16777216 * 2;
    float* b1v              = (float*)w;           w += (size_t)131072 * 4;
    float* wfv              = (float*)w;           w += (size_t)131072 * 4;
    float* vv               = (float*)w;           w += (size_t)4096 * 4;
    float* out              = (float*)d_out;

    k0_prep<<<514, 256, 0, stream>>>(w1s_W, W_gat, states, b1_W, wf_W, V1_W,
                                     w1sT, WgT, WsT, A_bf);

    k1_gat<<<1024, 256, 0, stream>>>(hidden_states, WgT, states, att_a, WsT,
        b1_b, wf_b, V1_b, V2_W, V2_b, g_bf, b1v, wfv, vv);

    dim3 grid2(32, 32);
    k2a_gemm<<<grid2, 256, 0, stream>>>(A_bf, w1sT, uncertainty, w1s_W, w1s_b, w1state);

    k2b_contract<<<1024, 256, 0, stream>>>(w1state, g_bf, agent_qs, b1v, wfv, vv, out);
}